// Round 1
// baseline (40.718 us; speedup 1.0000x reference)
//
#include <hip/hip_runtime.h>

// Fused quanvolution + FC + log_softmax for MI355X (gfx950).
//
// Math (per 2x2 patch, wires a=even col, b=odd col of a row):
//   za = cos(pa)*cos(xa) + sin(pa)*sin(xa)*sin(xb)
//   zb = cos(pb)*cos(xa)*cos(xb) + sin(pb)*sin(xb)
// rows 2r use params (p0,p1), rows 2r+1 use (p2,p3).
// q[b, ((y>>1)*14 + (col>>1))*4 + (y&1)*2 + (col&1)] = z
// logits = q @ fc_w.T + fc_b - bias; out = log_softmax(logits)

constexpr int WAVES = 4;   // waves per block
constexpr int IPW   = 4;   // images per wave
constexpr int BLOCK = WAVES * 64;

__global__ __launch_bounds__(BLOCK, 4)
void quanv_fused(const float* __restrict__ x,
                 const float* __restrict__ vqc,
                 const float* __restrict__ fc_w,
                 const float* __restrict__ fc_b,
                 const float* __restrict__ bias,
                 float* __restrict__ out,
                 int B)
{
    __shared__ float w_lds[7840];   // fc_w permuted to pixel order, k-major
    __shared__ float b_lds[10];     // fc_b - bias

    const int tid  = threadIdx.x;
    const int lane = tid & 63;
    const int wave = tid >> 6;

    // Stage fc_w into LDS, permuted so that LDS index p follows raw pixel
    // order: w_lds[k*784 + p] = fc_w[k*784 + qidx(p)].
    for (int e = tid; e < 7840; e += BLOCK) {
        int k   = e / 784;
        int p   = e - k * 784;
        int y   = p / 28;
        int col = p - y * 28;
        int qidx = (((y >> 1) * 14 + (col >> 1)) << 2) + ((y & 1) << 1) + (col & 1);
        w_lds[e] = fc_w[k * 784 + qidx];
    }
    if (tid < 10) b_lds[tid] = fc_b[tid] - bias[tid];
    __syncthreads();

    // circuit params (uniform): cos/sin once per thread
    const float C0 = __cosf(vqc[0]), S0 = __sinf(vqc[0]);
    const float C1 = __cosf(vqc[1]), S1 = __sinf(vqc[1]);
    const float C2 = __cosf(vqc[2]), S2 = __sinf(vqc[2]);
    const float C3 = __cosf(vqc[3]), S3 = __sinf(vqc[3]);

    const long imgBase = ((long)blockIdx.x * WAVES + wave) * IPW;

    float acc[IPW][10];
#pragma unroll
    for (int m = 0; m < IPW; ++m)
#pragma unroll
        for (int k = 0; k < 10; ++k) acc[m][k] = 0.f;

    // 196 float4 per image; 64 lanes -> 4 iterations (last partial)
#pragma unroll
    for (int t = 0; t < 4; ++t) {
        const int jv = t * 64 + lane;       // float4 index, 0..195
        if (jv < 196) {
            // pixel row y = (4*jv)/28 = jv/7; row parity picks param set
            const int   i  = (jv / 7) & 1;
            const float CA = i ? C2 : C0, SA = i ? S2 : S0;
            const float CB = i ? C3 : C1, SB = i ? S3 : S1;

            float q[IPW][4];
#pragma unroll
            for (int m = 0; m < IPW; ++m) {
                long img = imgBase + m;
                if (img >= B) img = B - 1;   // clamp (B divisible in practice)
                const float4 v = *reinterpret_cast<const float4*>(x + img * 784 + (long)jv * 4);
                const float sa = __sinf(v.x), ca = __cosf(v.x);
                const float sb = __sinf(v.y), cb = __cosf(v.y);
                const float sc = __sinf(v.z), cc = __cosf(v.z);
                const float sd = __sinf(v.w), cd = __cosf(v.w);
                q[m][0] = CA * ca + SA * (sa * sb);        // wire a, pair 0
                q[m][1] = CB * (ca * cb) + SB * sb;        // wire b, pair 0
                q[m][2] = CA * cc + SA * (sc * sd);        // wire a, pair 1
                q[m][3] = CB * (cc * cd) + SB * sd;        // wire b, pair 1
            }
#pragma unroll
            for (int k = 0; k < 10; ++k) {
                const float4 w = *reinterpret_cast<const float4*>(&w_lds[k * 784 + jv * 4]);
#pragma unroll
                for (int m = 0; m < IPW; ++m) {
                    acc[m][k] += q[m][0] * w.x + q[m][1] * w.y
                               + q[m][2] * w.z + q[m][3] * w.w;
                }
            }
        }
    }

    // butterfly reduce across the wave (all lanes end with the full sums)
#pragma unroll
    for (int m = 0; m < IPW; ++m) {
#pragma unroll
        for (int k = 0; k < 10; ++k) {
            float v = acc[m][k];
#pragma unroll
            for (int off = 32; off > 0; off >>= 1)
                v += __shfl_xor(v, off, 64);
            acc[m][k] = v;
        }
    }

    // log_softmax + store (lanes 0..9 write coalesced)
#pragma unroll
    for (int m = 0; m < IPW; ++m) {
        const long img = imgBase + m;
        float lg[10];
#pragma unroll
        for (int k = 0; k < 10; ++k) lg[k] = acc[m][k] + b_lds[k];
        float mx = lg[0];
#pragma unroll
        for (int k = 1; k < 10; ++k) mx = fmaxf(mx, lg[k]);
        float s = 0.f;
#pragma unroll
        for (int k = 0; k < 10; ++k) s += __expf(lg[k] - mx);
        const float lse = mx + __logf(s);
        float v = lg[0];
#pragma unroll
        for (int k = 1; k < 10; ++k) v = (lane == k) ? lg[k] : v;
        if (lane < 10 && img < B) out[img * 10 + lane] = v - lse;
    }
}

extern "C" void kernel_launch(void* const* d_in, const int* in_sizes, int n_in,
                              void* d_out, int out_size, void* d_ws, size_t ws_size,
                              hipStream_t stream) {
    const float* x    = (const float*)d_in[0];
    const float* vqc  = (const float*)d_in[1];
    const float* fc_w = (const float*)d_in[2];
    const float* fc_b = (const float*)d_in[3];
    const float* bias = (const float*)d_in[4];
    float* outp = (float*)d_out;

    const int B = in_sizes[0] / 784;
    const int nblocks = (B + WAVES * IPW - 1) / (WAVES * IPW);
    hipLaunchKernelGGL(quanv_fused, dim3(nblocks), dim3(BLOCK), 0, stream,
                       x, vqc, fc_w, fc_b, bias, outp, B);
}

// Round 2
// 27.059 us; speedup vs baseline: 1.5047x; 1.5047x over previous
//
#include <hip/hip_runtime.h>

// Fused quanvolution + FC + log_softmax for MI355X (gfx950).
//
// Decomposition: lane j owns PATCH j (2x2 pixels). It loads two float2s
// (rows 2r and 2r+1 of the patch); the resulting q-quad is q[4j..4j+3],
// which is fc_w's NATIVE column order -> no weight permutation anywhere.
//
//   za = cos(pa)*cos(xa) + sin(pa)*sin(xa)*sin(xb)
//   zb = cos(pb)*cos(xa)*cos(xb) + sin(pb)*sin(xb)
// pair (x0,x1) uses (p0,p1); pair (x2,x3) uses (p2,p3).
// logits = q @ fc_w.T + (fc_b - bias); out = log_softmax(logits)

constexpr int WAVES = 4;   // waves per block
constexpr int IPW   = 4;   // images per wave
constexpr int BLOCK = WAVES * 64;

__global__ __launch_bounds__(BLOCK, 4)
void quanv_fused(const float* __restrict__ x,
                 const float* __restrict__ vqc,
                 const float* __restrict__ fc_w,
                 const float* __restrict__ fc_b,
                 const float* __restrict__ bias,
                 float* __restrict__ out,
                 int B)
{
    __shared__ float w_lds[7840];   // fc_w verbatim (k-major, native order)
    __shared__ float b_lds[10];     // fc_b - bias

    const int tid  = threadIdx.x;
    const int lane = tid & 63;
    const int wave = tid >> 6;
    const int imgBase = (blockIdx.x * WAVES + wave) * IPW;

    // ---- issue t=0 x loads FIRST so their latency overlaps the staging ----
    float2 cxa[IPW], cxb[IPW];
    {
        const int j   = lane;                      // t=0: j < 196 always
        const int off = 56 * (j / 14) + 2 * (j % 14);
        #pragma unroll
        for (int m = 0; m < IPW; ++m) {
            int img = imgBase + m; if (img >= B) img = B - 1;
            const float* p = x + img * 784 + off;
            cxa[m] = *reinterpret_cast<const float2*>(p);       // row 2r
            cxb[m] = *reinterpret_cast<const float2*>(p + 28);  // row 2r+1
        }
    }

    // ---- weight staging: purely coalesced float4 copy, no permutation ----
    #pragma unroll
    for (int it = 0; it < 8; ++it) {
        const int v4 = it * BLOCK + tid;           // 1960 float4 total
        if (v4 < 1960)
            reinterpret_cast<float4*>(w_lds)[v4] =
                reinterpret_cast<const float4*>(fc_w)[v4];
    }
    if (tid < 10) b_lds[tid] = fc_b[tid] - bias[tid];

    // circuit params (uniform)
    const float C0 = __cosf(vqc[0]), S0 = __sinf(vqc[0]);
    const float C1 = __cosf(vqc[1]), S1 = __sinf(vqc[1]);
    const float C2 = __cosf(vqc[2]), S2 = __sinf(vqc[2]);
    const float C3 = __cosf(vqc[3]), S3 = __sinf(vqc[3]);

    __syncthreads();

    float acc[IPW][10];
    #pragma unroll
    for (int m = 0; m < IPW; ++m)
        #pragma unroll
        for (int k = 0; k < 10; ++k) acc[m][k] = 0.f;

    // 196 patches over 64 lanes -> 4 iterations; 1-ahead pipelined loads
    #pragma unroll
    for (int t = 0; t < 4; ++t) {
        float2 nxa[IPW], nxb[IPW];
        if (t < 3) {                                // prefetch t+1
            const int j2  = (t + 1) * 64 + lane;
            const int jc2 = j2 < 196 ? j2 : 195;
            const int off = 56 * (jc2 / 14) + 2 * (jc2 % 14);
            #pragma unroll
            for (int m = 0; m < IPW; ++m) {
                int img = imgBase + m; if (img >= B) img = B - 1;
                const float* p = x + img * 784 + off;
                nxa[m] = *reinterpret_cast<const float2*>(p);
                nxb[m] = *reinterpret_cast<const float2*>(p + 28);
            }
        }

        const int j  = t * 64 + lane;
        const int jc = j < 196 ? j : 195;
        const float msk = (t == 3) ? (j < 196 ? 1.f : 0.f) : 1.f; // folds to 1 for t<3

        float q[IPW][4];
        #pragma unroll
        for (int m = 0; m < IPW; ++m) {
            float sa, ca, sb, cb, sc, cc, sd, cd;
            __sincosf(cxa[m].x, &sa, &ca);
            __sincosf(cxa[m].y, &sb, &cb);
            __sincosf(cxb[m].x, &sc, &cc);
            __sincosf(cxb[m].y, &sd, &cd);
            q[m][0] = (C0 * ca + S0 * (sa * sb)) * msk;
            q[m][1] = (C1 * (ca * cb) + S1 * sb) * msk;
            q[m][2] = (C2 * cc + S2 * (sc * sd)) * msk;
            q[m][3] = (C3 * (cc * cd) + S3 * sd) * msk;
        }

        #pragma unroll
        for (int k = 0; k < 10; ++k) {
            const float4 w = *reinterpret_cast<const float4*>(&w_lds[k * 784 + 4 * jc]);
            #pragma unroll
            for (int m = 0; m < IPW; ++m)
                acc[m][k] += q[m][0] * w.x + q[m][1] * w.y
                           + q[m][2] * w.z + q[m][3] * w.w;
        }

        if (t < 3) {
            #pragma unroll
            for (int m = 0; m < IPW; ++m) { cxa[m] = nxa[m]; cxb[m] = nxb[m]; }
        }
    }

    // wave butterfly reduce (all lanes end with full sums)
    #pragma unroll
    for (int m = 0; m < IPW; ++m)
        #pragma unroll
        for (int k = 0; k < 10; ++k) {
            float v = acc[m][k];
            #pragma unroll
            for (int off = 32; off > 0; off >>= 1)
                v += __shfl_xor(v, off, 64);
            acc[m][k] = v;
        }

    // log_softmax + store
    #pragma unroll
    for (int m = 0; m < IPW; ++m) {
        const int img = imgBase + m;
        float lg[10];
        #pragma unroll
        for (int k = 0; k < 10; ++k) lg[k] = acc[m][k] + b_lds[k];
        float mx = lg[0];
        #pragma unroll
        for (int k = 1; k < 10; ++k) mx = fmaxf(mx, lg[k]);
        float s = 0.f;
        #pragma unroll
        for (int k = 0; k < 10; ++k) s += __expf(lg[k] - mx);
        const float lse = mx + __logf(s);
        float v = lg[0];
        #pragma unroll
        for (int k = 1; k < 10; ++k) v = (lane == k) ? lg[k] : v;
        if (lane < 10 && img < B) out[img * 10 + lane] = v - lse;
    }
}

extern "C" void kernel_launch(void* const* d_in, const int* in_sizes, int n_in,
                              void* d_out, int out_size, void* d_ws, size_t ws_size,
                              hipStream_t stream) {
    const float* x    = (const float*)d_in[0];
    const float* vqc  = (const float*)d_in[1];
    const float* fc_w = (const float*)d_in[2];
    const float* fc_b = (const float*)d_in[3];
    const float* bias = (const float*)d_in[4];
    float* outp = (float*)d_out;

    const int B = in_sizes[0] / 784;
    const int nblocks = (B + WAVES * IPW - 1) / (WAVES * IPW);
    hipLaunchKernelGGL(quanv_fused, dim3(nblocks), dim3(BLOCK), 0, stream,
                       x, vqc, fc_w, fc_b, bias, outp, B);
}

// Round 3
// 17.014 us; speedup vs baseline: 2.3932x; 1.5905x over previous
//
#include <hip/hip_runtime.h>
#include <hip/hip_bf16.h>

// Fused quanvolution + FC + log_softmax via MFMA (gfx950).
//
// logits[16 imgs][10] = q[16][784] @ w[784][10]  using mfma_f32_16x16x32_bf16.
// Lane l: i16 = l&15 (A row = image / B col = class), g = l>>4 (k-subgroup).
// A frag: 8 consecutive k = 2 adjacent patches = two aligned float4 x-loads.
// B frag: w[class][k..k+7] from global (L2-hot), preconverted to bf16 regs.
// K padded 784 -> 800 (25 kblocks of 32); 4 waves split the 25 kblocks
// (wave w takes kb = w, w+4, ...), partials combined through 3KB LDS.
// C frag (m89-verified): col = lane&15, row = (lane>>4)*4 + reg.

typedef __attribute__((ext_vector_type(8))) short short8;
typedef __attribute__((ext_vector_type(4))) float f32x4;

constexpr int WAVES = 4;
constexpr int BLOCK = WAVES * 64;
constexpr int IMGS  = 16;     // images per block
constexpr int NITER = 7;      // ceil(25 kblocks / 4 waves)

static __device__ __forceinline__ short f2bf(float f) {
    union { float f; unsigned u; } v; v.f = f;
    unsigned r = v.u + 0x7fffu + ((v.u >> 16) & 1u);   // round-to-nearest-even
    return (short)(r >> 16);
}

__global__ __launch_bounds__(BLOCK, 4)
void quanv_mfma(const float* __restrict__ x,
                const float* __restrict__ vqc,
                const float* __restrict__ fc_w,
                const float* __restrict__ fc_b,
                const float* __restrict__ bias,
                float* __restrict__ out,
                int B)
{
    __shared__ float cpart[3][64 * 4];   // K-split partial C exchange (3 KB)

    const int tid  = threadIdx.x;
    const int lane = tid & 63;
    const int wv   = tid >> 6;
    const int i16  = lane & 15;          // A row (image) / B col (class)
    const int g    = lane >> 4;          // k-subgroup within the 32-k block

    const int imgBase = blockIdx.x * IMGS;
    const int imgLane = imgBase + i16;                       // image this lane loads
    const long xb = (long)(imgLane < B ? imgLane : B - 1) * 784;

    // ---- circuit params ----
    float S0, C0, S1, C1, S2, C2, S3, C3;
    __sincosf(vqc[0], &S0, &C0);
    __sincosf(vqc[1], &S1, &C1);
    __sincosf(vqc[2], &S2, &C2);
    __sincosf(vqc[3], &S3, &C3);

    // ---- preload B fragments (w^T chunks) into registers, bf16 ----
    const int ncl = (i16 < 10) ? i16 : 9;        // clamp class row (garbage cols masked later)
    short8 bf[NITER];
    #pragma unroll
    for (int I = 0; I < NITER; ++I) {
        const int kb = wv + 4 * I;
        int k = kb * 32 + g * 8;
        if (k > 776) k = 776;                    // keep float4s in-bounds; A=0 covers k>=784
        const float4 lo = *reinterpret_cast<const float4*>(fc_w + ncl * 784 + k);
        const float4 hi = *reinterpret_cast<const float4*>(fc_w + ncl * 784 + k + 4);
        short8 t;
        t[0] = f2bf(lo.x); t[1] = f2bf(lo.y); t[2] = f2bf(lo.z); t[3] = f2bf(lo.w);
        t[4] = f2bf(hi.x); t[5] = f2bf(hi.y); t[6] = f2bf(hi.z); t[7] = f2bf(hi.w);
        bf[I] = t;
    }

    // x byte-offset (in floats) for iteration I: patches j0 = kb*8 + 2g, j0+1
    auto xoff = [&](int I) -> int {
        const int kb = wv + 4 * I;
        int j0 = kb * 8 + 2 * g;
        if (j0 > 194) j0 = 0;                    // clamp (masked below)
        const int r = j0 / 14, c = j0 - 14 * r;  // j0 even -> c even -> 16B aligned
        return 56 * r + 2 * c;
    };

    f32x4 acc = {0.f, 0.f, 0.f, 0.f};

    float4 curT = *reinterpret_cast<const float4*>(x + xb + xoff(0));
    float4 curB = *reinterpret_cast<const float4*>(x + xb + xoff(0) + 28);

    #pragma unroll
    for (int I = 0; I < NITER; ++I) {
        float4 nxT, nxB;
        if (I < NITER - 1) {                     // 1-ahead prefetch
            const int o = xoff(I + 1);
            nxT = *reinterpret_cast<const float4*>(x + xb + o);
            nxB = *reinterpret_cast<const float4*>(x + xb + o + 28);
        }

        const int   kb  = wv + 4 * I;
        const int   j0  = kb * 8 + 2 * g;
        const float msk = (j0 <= 194) ? 1.f : 0.f;

        // trig for 2 patches (8 pixels)
        float sA, cA, sB, cB, sC, cC, sD, cD;
        __sincosf(curT.x, &sA, &cA);  __sincosf(curT.y, &sB, &cB);
        __sincosf(curB.x, &sC, &cC);  __sincosf(curB.y, &sD, &cD);
        const float q0 = (C0 * cA + S0 * (sA * sB)) * msk;
        const float q1 = (C1 * (cA * cB) + S1 * sB) * msk;
        const float q2 = (C2 * cC + S2 * (sC * sD)) * msk;
        const float q3 = (C3 * (cC * cD) + S3 * sD) * msk;
        __sincosf(curT.z, &sA, &cA);  __sincosf(curT.w, &sB, &cB);
        __sincosf(curB.z, &sC, &cC);  __sincosf(curB.w, &sD, &cD);
        const float q4 = (C0 * cA + S0 * (sA * sB)) * msk;
        const float q5 = (C1 * (cA * cB) + S1 * sB) * msk;
        const float q6 = (C2 * cC + S2 * (sC * sD)) * msk;
        const float q7 = (C3 * (cC * cD) + S3 * sD) * msk;

        short8 a;
        a[0] = f2bf(q0); a[1] = f2bf(q1); a[2] = f2bf(q2); a[3] = f2bf(q3);
        a[4] = f2bf(q4); a[5] = f2bf(q5); a[6] = f2bf(q6); a[7] = f2bf(q7);

        acc = __builtin_amdgcn_mfma_f32_16x16x32_bf16(a, bf[I], acc, 0, 0, 0);

        curT = nxT; curB = nxB;
    }

    // ---- K-split combine through LDS ----
    if (wv > 0)
        *reinterpret_cast<f32x4*>(&cpart[wv - 1][lane * 4]) = acc;
    __syncthreads();

    if (wv == 0) {
        #pragma unroll
        for (int p = 0; p < 3; ++p) {
            const f32x4 o = *reinterpret_cast<const f32x4*>(&cpart[p][lane * 4]);
            acc += o;
        }
        const float bk = (i16 < 10) ? (fc_b[i16] - bias[i16]) : 0.f;

        #pragma unroll
        for (int r = 0; r < 4; ++r) {
            const float lg = acc[r] + bk;
            // max over classes (lanes i16=0..9 within each 16-lane group)
            float mx = (i16 < 10) ? lg : -3.0e38f;
            #pragma unroll
            for (int off = 1; off < 16; off <<= 1)
                mx = fmaxf(mx, __shfl_xor(mx, off, 64));
            float s = (i16 < 10) ? __expf(lg - mx) : 0.f;
            #pragma unroll
            for (int off = 1; off < 16; off <<= 1)
                s += __shfl_xor(s, off, 64);
            const int im = imgBase + g * 4 + r;     // C row = g*4 + reg  [m89]
            if (i16 < 10 && im < B)
                out[(long)im * 10 + i16] = lg - mx - __logf(s);
        }
    }
}

extern "C" void kernel_launch(void* const* d_in, const int* in_sizes, int n_in,
                              void* d_out, int out_size, void* d_ws, size_t ws_size,
                              hipStream_t stream) {
    const float* x    = (const float*)d_in[0];
    const float* vqc  = (const float*)d_in[1];
    const float* fc_w = (const float*)d_in[2];
    const float* fc_b = (const float*)d_in[3];
    const float* bias = (const float*)d_in[4];
    float* outp = (float*)d_out;

    const int B = in_sizes[0] / 784;
    const int nblocks = (B + IMGS - 1) / IMGS;
    hipLaunchKernelGGL(quanv_mfma, dim3(nblocks), dim3(BLOCK), 0, stream,
                       x, vqc, fc_w, fc_b, bias, outp, B);
}